// Round 6
// baseline (252.329 us; speedup 1.0000x reference)
//
#include <hip/hip_runtime.h>
#include <hip/hip_bf16.h>

#define N_NODES 16384
#define N_EDGES 262144
#define GD 300        // real feature dim
#define DP 320        // padded feature dim (pads are exact zeros)
#define N_GRAPHS 64
#define NTILE 5       // 5 column tiles of 64

typedef short bf16x8 __attribute__((ext_vector_type(8)));
typedef float f32x4 __attribute__((ext_vector_type(4)));

__device__ static inline unsigned short f2bf(float v) {
  __hip_bfloat16 b = __float2bfloat16(v);
  return __builtin_bit_cast(unsigned short, b);
}
__device__ static inline float bf2f(unsigned short u) {
  return __bfloat162float(__builtin_bit_cast(__hip_bfloat16, u));
}

// ================= bf16 MFMA GEMM v2 — barrier-free K loop =================
// C[M,DP] = act(A[M,DP](bf16) @ W + bias), Wt[n][k] pre-transposed bf16.
// BM=64, BN=320 (full width), 512 threads = 8 waves (2 row x 4 col groups),
// per-wave 2x5 frags of 16x16x32, K=320 in 10 k-steps.
// A staged ONCE in LDS (coalesced loads + ds_write, 656B padded pitch ->
// conflict-free ds_read_b128). B streamed global->VGPR, 2-deep k prefetch.
// ONE barrier total; no vmcnt drains in the loop.
constexpr int PITCH = 656;  // 640B row + 16B pad: r*656%128 = 16*((r)%8) banks
constexpr size_t WSZ = (size_t)DP * DP;

template <bool RELU, bool TILED, bool RO>
__global__ __launch_bounds__(512, 2) void gemm_v2(
    const unsigned short* __restrict__ A, const unsigned short* __restrict__ Wt,
    const float* __restrict__ biasP, unsigned short* __restrict__ C,
    const float* __restrict__ Wro, const float* __restrict__ bro,
    const int* __restrict__ gid, float* __restrict__ out) {
  __shared__ __align__(16) char ldsA[64 * PITCH];  // 41984 B
  __shared__ float wroL[2 * DP];
  __shared__ float rowacc[2 * 64];
  __shared__ float binsL[2 * N_GRAPHS];

  const int bm = blockIdx.y * 64;
  const int t = threadIdx.x;
  const int w = t >> 6, l = t & 63;
  const int wr = w & 1;        // row group: rows wr*32..+31
  const int wc = w >> 1;       // col group: cols wc*80..+79
  const int q = l >> 4;        // k-quarter within frag
  const int cl = l & 15;       // row/col within frag

  if (RO) {
    for (int i = t; i < DP; i += 512) {
      wroL[2 * i] = (i < GD) ? Wro[2 * i] : 0.f;
      wroL[2 * i + 1] = (i < GD) ? Wro[2 * i + 1] : 0.f;
    }
    if (t < 128) rowacc[t] = 0.f;
    if (t < 2 * N_GRAPHS) binsL[t] = 0.f;
  }

  // ---- stage A (64 x 320 bf16) into padded LDS; fully coalesced ----
#pragma unroll
  for (int p = 0; p < 5; ++p) {
    int i = t + 512 * p;             // 0..2559 slot index
    int r = i / 40, s = i - r * 40;  // row, 16B-slot
    bf16x8 v = *(const bf16x8*)(A + (size_t)(bm + r) * DP + s * 8);
    *(bf16x8*)(ldsA + r * PITCH + s * 16) = v;
  }

  // ---- B fragment base + prefetch k-groups 0,1 (independent of LDS) ----
  const unsigned short* bp0 = Wt + (size_t)(wc * 80 + cl) * DP + q * 8;
  bf16x8 b0[5], b1[5];
#pragma unroll
  for (int n = 0; n < 5; ++n) b0[n] = *(const bf16x8*)(bp0 + (size_t)n * 16 * DP);
#pragma unroll
  for (int n = 0; n < 5; ++n) b1[n] = *(const bf16x8*)(bp0 + (size_t)n * 16 * DP + 32);

  f32x4 acc[2][5] = {};
  __syncthreads();  // the only block-wide barrier before the epilogue

  const char* aB = ldsA + q * 16;
  const int r0 = wr * 32 + cl;       // m=0 frag row
  const int r1 = r0 + 16;            // m=1 frag row

#define KSTEP(KK, BB)                                                         \
  {                                                                           \
    bf16x8 a0 = *(const bf16x8*)(aB + r0 * PITCH + (KK) * 64);                \
    bf16x8 a1 = *(const bf16x8*)(aB + r1 * PITCH + (KK) * 64);                \
    _Pragma("unroll") for (int n = 0; n < 5; ++n)                             \
        acc[0][n] = __builtin_amdgcn_mfma_f32_16x16x32_bf16(a0, BB[n],        \
                                                            acc[0][n], 0, 0, 0); \
    _Pragma("unroll") for (int n = 0; n < 5; ++n)                             \
        acc[1][n] = __builtin_amdgcn_mfma_f32_16x16x32_bf16(a1, BB[n],        \
                                                            acc[1][n], 0, 0, 0); \
    if ((KK) < 8) {                                                           \
      _Pragma("unroll") for (int n = 0; n < 5; ++n)                           \
          BB[n] = *(const bf16x8*)(bp0 + (size_t)n * 16 * DP + ((KK) + 2) * 32); \
    }                                                                         \
  }
  KSTEP(0, b0) KSTEP(1, b1) KSTEP(2, b0) KSTEP(3, b1) KSTEP(4, b0)
  KSTEP(5, b1) KSTEP(6, b0) KSTEP(7, b1) KSTEP(8, b0) KSTEP(9, b1)
#undef KSTEP

  if (!RO) {
#pragma unroll
    for (int m = 0; m < 2; ++m) {
#pragma unroll
      for (int n = 0; n < 5; ++n) {
        int col = wc * 80 + n * 16 + cl;
        float bv = biasP[col];
#pragma unroll
        for (int r = 0; r < 4; ++r) {
          int row = bm + wr * 32 + m * 16 + q * 4 + r;
          float v = acc[m][n][r] + bv;
          if (RELU) v = fmaxf(v, 0.f);
          size_t idx;
          if (TILED)  // column-tile-major Mt[tile][row][64] for SpMM
            idx = ((size_t)(col >> 6) * N_NODES + row) * 64 + (col & 63);
          else
            idx = (size_t)row * DP + col;
          C[idx] = f2bf(v);
        }
      }
    }
  } else {
    // fused readout: d = relu(acc+bias) . Wro -> softmax -> graph bins
    float bv[5];
#pragma unroll
    for (int n = 0; n < 5; ++n) bv[n] = biasP[wc * 80 + n * 16 + cl];
#pragma unroll
    for (int m = 0; m < 2; ++m) {
#pragma unroll
      for (int r = 0; r < 4; ++r) {
        float s0 = 0.f, s1 = 0.f;
#pragma unroll
        for (int n = 0; n < 5; ++n) {
          int col = wc * 80 + n * 16 + cl;
          float v = fmaxf(acc[m][n][r] + bv[n], 0.f);
          s0 += v * wroL[2 * col];
          s1 += v * wroL[2 * col + 1];
        }
#pragma unroll
        for (int off = 1; off < 16; off <<= 1) {
          s0 += __shfl_xor(s0, off);
          s1 += __shfl_xor(s1, off);
        }
        if (cl == 0) {
          int row = wr * 32 + m * 16 + q * 4 + r;
          atomicAdd(&rowacc[2 * row], s0);
          atomicAdd(&rowacc[2 * row + 1], s1);
        }
      }
    }
    __syncthreads();
    if (t < 64) {
      float d0 = rowacc[2 * t] + bro[0];
      float d1 = rowacc[2 * t + 1] + bro[1];
      float mx = fmaxf(d0, d1);
      float e0 = expf(d0 - mx), e1 = expf(d1 - mx);
      float inv = 1.f / (e0 + e1);
      int g = gid[bm + t];
      atomicAdd(&binsL[2 * g], e0 * inv);
      atomicAdd(&binsL[2 * g + 1], e1 * inv);
    }
    __syncthreads();
    if (t < 2 * N_GRAPHS) {
      float v = binsL[t];
      if (v != 0.f) atomicAdd(&out[t], v);
    }
  }
}

// ================= CSR build =================
__global__ void hist_kernel(const int* __restrict__ dst, int* __restrict__ cnt) {
  int e = blockIdx.x * blockDim.x + threadIdx.x;
  if (e < N_EDGES) atomicAdd(&cnt[dst[e]], 1);
}

__global__ __launch_bounds__(256) void scan_kernel(
    const int* __restrict__ cnt, int* __restrict__ row_ptr, int* __restrict__ row_fill,
    float* __restrict__ out, int out_n) {
  if (threadIdx.x < out_n) out[threadIdx.x] = 0.f;  // zero d_out (fused)
  __shared__ int sums[256];
  const int t = threadIdx.x;
  const int base = t * 64;
  int s = 0;
  for (int i = 0; i < 64; ++i) s += cnt[base + i];
  sums[t] = s;
  __syncthreads();
  for (int off = 1; off < 256; off <<= 1) {
    int x = (t >= off) ? sums[t - off] : 0;
    __syncthreads();
    sums[t] += x;
    __syncthreads();
  }
  int run = sums[t] - s;
  for (int i = 0; i < 64; ++i) {
    int c = cnt[base + i];
    row_ptr[base + i] = run;
    row_fill[base + i] = run;
    run += c;
  }
  if (t == 255) row_ptr[N_NODES] = run;
}

__global__ void scatter_kernel(const int* __restrict__ src, const int* __restrict__ dst,
                               int* __restrict__ row_fill, int* __restrict__ csr_src) {
  int e = blockIdx.x * blockDim.x + threadIdx.x;
  if (e >= N_EDGES) return;
  int pos = atomicAdd(&row_fill[dst[e]], 1);
  csr_src[pos] = src[e];
}

// ========== SpMM aggregate: tiled gather, L2-resident per column phase ======
__global__ __launch_bounds__(256) void spmm_tiled(
    const unsigned short* __restrict__ Mt, const int* __restrict__ row_ptr,
    const int* __restrict__ csr_src, unsigned short* __restrict__ agg) {
  const int tile = blockIdx.y;
  const int wv = threadIdx.x >> 6;
  const int l = threadIdx.x & 63;
  const int g = l >> 3;    // node group
  const int cs = l & 7;    // 16B slot within 128B slice
  const int node = blockIdx.x * 32 + wv * 8 + g;
  const unsigned short* base = Mt + (size_t)tile * N_NODES * 64 + cs * 8;

  int j = row_ptr[node];
  const int j1 = row_ptr[node + 1];
  float acc[8] = {};
  for (; j + 4 <= j1; j += 4) {
    int s0 = csr_src[j], s1 = csr_src[j + 1];
    int s2 = csr_src[j + 2], s3 = csr_src[j + 3];
    bf16x8 v0 = *(const bf16x8*)(base + (size_t)s0 * 64);
    bf16x8 v1 = *(const bf16x8*)(base + (size_t)s1 * 64);
    bf16x8 v2 = *(const bf16x8*)(base + (size_t)s2 * 64);
    bf16x8 v3 = *(const bf16x8*)(base + (size_t)s3 * 64);
#pragma unroll
    for (int i = 0; i < 8; ++i)
      acc[i] += (bf2f(v0[i]) + bf2f(v1[i])) + (bf2f(v2[i]) + bf2f(v3[i]));
  }
  for (; j < j1; ++j) {
    bf16x8 v = *(const bf16x8*)(base + (size_t)csr_src[j] * 64);
#pragma unroll
    for (int i = 0; i < 8; ++i) acc[i] += bf2f(v[i]);
  }
  bf16x8 o;
#pragma unroll
  for (int i = 0; i < 8; ++i) o[i] = f2bf(acc[i]);
  *(bf16x8*)(agg + (size_t)node * DP + tile * 64 + cs * 8) = o;
}

// ================= conversions =================
__global__ void conv_feats(const float* __restrict__ nf, unsigned short* __restrict__ X) {
  int idx = blockIdx.x * 256 + threadIdx.x;  // over N_NODES * 40 groups of 8
  int r = idx / 40, j = idx - r * 40;
  int c0 = j * 8;
  const float* rp = nf + (size_t)r * GD + c0;
  bf16x8 o;
  if (c0 + 8 <= GD) {
    float4 a = *(const float4*)rp;
    float4 b = *(const float4*)(rp + 4);
    o[0] = f2bf(a.x); o[1] = f2bf(a.y); o[2] = f2bf(a.z); o[3] = f2bf(a.w);
    o[4] = f2bf(b.x); o[5] = f2bf(b.y); o[6] = f2bf(b.z); o[7] = f2bf(b.w);
  } else {
#pragma unroll
    for (int i = 0; i < 8; ++i) {
      int c = c0 + i;
      o[i] = f2bf(c < GD ? rp[i] : 0.f);
    }
  }
  *(bf16x8*)(X + (size_t)idx * 8) = o;
}

struct WPtrs {
  const float* W[7];   // [0..5] -> transposed (Wf1,Wo1,Wf2,Wo2,Wf3,Wo3), [6]=Wlift copy
  const float* b[5];   // biases for slots 3..7 (bo1,bf2,bo2,bf3,bo3)
};

// Wt slots: 0=Wc_t(computed), 1=Wf1t, 2=Wlift copy, 3=Wo1t, 4=Wf2t, 5=Wo2t,
// 6=Wf3t, 7=Wo3t. biasP slots: 0=bc, 1=zeros, 3..7 per Wt.
// LDS-tile transpose: coalesced fp32 reads AND coalesced bf16 writes.
__global__ __launch_bounds__(256) void conv_w(WPtrs p, unsigned short* __restrict__ Wt,
                                              float* __restrict__ biasP) {
  __shared__ unsigned short ld[64][33];
  const int wi = blockIdx.y;                  // 0..6
  const int kt = blockIdx.x / 5;              // 10 k-tiles of 32
  const int nt = blockIdx.x - kt * 5;         // 5 n-tiles of 64
  const int k0 = kt * 32, n0 = nt * 64;
  const int t = threadIdx.x;
  const float* W = p.W[wi];

  if (wi == 6) {  // plain copy (keep orientation), coalesced
#pragma unroll
    for (int ps = 0; ps < 8; ++ps) {
      int idx = t + 256 * ps;
      int rr = idx >> 6, cc = idx & 63;
      float v = (k0 + rr < GD && n0 + cc < GD) ? W[(size_t)(k0 + rr) * GD + n0 + cc] : 0.f;
      Wt[2 * WSZ + (size_t)(k0 + rr) * DP + n0 + cc] = f2bf(v);
    }
    return;
  }
  const int slot = (wi == 0) ? 1 : wi + 2;
#pragma unroll
  for (int ps = 0; ps < 8; ++ps) {
    int idx = t + 256 * ps;
    int rr = idx >> 6, cc = idx & 63;       // rr: k in tile, cc: n in tile
    float v = (k0 + rr < GD && n0 + cc < GD) ? W[(size_t)(k0 + rr) * GD + n0 + cc] : 0.f;
    ld[cc][rr] = f2bf(v);
  }
  __syncthreads();
#pragma unroll
  for (int ps = 0; ps < 8; ++ps) {
    int idx = t + 256 * ps;
    int nn = idx >> 5, kk = idx & 31;
    Wt[(size_t)slot * WSZ + (size_t)(n0 + nn) * DP + k0 + kk] = ld[nn][kk];
  }
  // fused bias copies for slots 3..7
  if (blockIdx.x == 0 && wi >= 1) {
    for (int i = t; i < DP; i += 256)
      biasP[(size_t)(wi + 2) * DP + i] = (i < GD) ? p.b[wi - 1][i] : 0.f;
  }
}

// bc[n] = bl @ Wf1[:,n] + bf1[n], wave-parallel using transposed bf16 Wf1t rows
__global__ __launch_bounds__(512) void bias_fuse(
    const unsigned short* __restrict__ Wf1t, const float* __restrict__ bl,
    const float* __restrict__ bf1, float* __restrict__ biasP) {
  const int w = threadIdx.x >> 6, l = threadIdx.x & 63;
  const int n = blockIdx.x * 8 + w;  // 0..319
  float s = 0.f;
  for (int j = l; j < GD; j += 64) s += bf2f(Wf1t[(size_t)n * DP + j]) * bl[j];
#pragma unroll
  for (int off = 32; off; off >>= 1) s += __shfl_down(s, off);
  if (l == 0) {
    biasP[n] = s + ((n < GD) ? bf1[n] : 0.f);  // slot 0 = bc
    biasP[DP + n] = 0.f;                        // slot 1 = zeros
  }
}

// ================= host =================
extern "C" void kernel_launch(void* const* d_in, const int* in_sizes, int n_in,
                              void* d_out, int out_size, void* d_ws, size_t ws_size,
                              hipStream_t stream) {
  const float* node_feats = (const float*)d_in[0];
  const float* W_lift = (const float*)d_in[1];
  const float* b_lift = (const float*)d_in[2];
  const float* Wf1 = (const float*)d_in[3];
  const float* bf1 = (const float*)d_in[4];
  const float* W_ro = (const float*)d_in[15];
  const float* b_ro = (const float*)d_in[16];
  const int* src = (const int*)d_in[17];
  const int* dst = (const int*)d_in[18];
  const int* gid = (const int*)d_in[19];
  float* out = (float*)d_out;

  WPtrs wp;
  wp.W[0] = Wf1;
  wp.W[1] = (const float*)d_in[5];   wp.b[0] = (const float*)d_in[6];   // Wo1 -> 3
  wp.W[2] = (const float*)d_in[7];   wp.b[1] = (const float*)d_in[8];   // Wf2 -> 4
  wp.W[3] = (const float*)d_in[9];   wp.b[2] = (const float*)d_in[10];  // Wo2 -> 5
  wp.W[4] = (const float*)d_in[11];  wp.b[3] = (const float*)d_in[12];  // Wf3 -> 6
  wp.W[5] = (const float*)d_in[13];  wp.b[4] = (const float*)d_in[14];  // Wo3 -> 7
  wp.W[6] = W_lift;                  // -> slot 2 (copy)

  char* p = (char*)d_ws;
  unsigned short* X = (unsigned short*)p;  p += (size_t)N_NODES * DP * 2;
  unsigned short* Y = (unsigned short*)p;  p += (size_t)N_NODES * DP * 2;
  unsigned short* Wt = (unsigned short*)p; p += (size_t)8 * WSZ * 2;
  float* biasP = (float*)p;                p += 8 * DP * 4;
  int* cnt = (int*)p;                      p += N_NODES * 4;
  int* row_ptr = (int*)p;                  p += (N_NODES + 16) * 4;
  int* row_fill = (int*)p;                 p += N_NODES * 4;
  int* csr_src = (int*)p;                  p += N_EDGES * 4;

  // --- CSR build (out-zeroing fused into scan) ---
  hipMemsetAsync(cnt, 0, N_NODES * sizeof(int), stream);
  hist_kernel<<<N_EDGES / 256, 256, 0, stream>>>(dst, cnt);
  scan_kernel<<<1, 256, 0, stream>>>(cnt, row_ptr, row_fill, out, out_size);
  scatter_kernel<<<N_EDGES / 256, 256, 0, stream>>>(src, dst, row_fill, csr_src);

  // --- conversions + lift-fold precompute ---
  conv_feats<<<(N_NODES * 40) / 256, 256, 0, stream>>>(node_feats, X);
  conv_w<<<dim3(50, 7), 256, 0, stream>>>(wp, Wt, biasP);
  bias_fuse<<<40, 512, 0, stream>>>(Wt + 1 * WSZ, b_lift, bf1, biasP);
  // Wc_t = Wf1t @ Wlift  (M=320, 5 blocks)
  gemm_v2<false, false, false><<<dim3(1, 5), 512, 0, stream>>>(
      Wt + 1 * WSZ, Wt + 2 * WSZ, biasP + 1 * DP, Wt + 0 * WSZ,
      nullptr, nullptr, nullptr, nullptr);

  dim3 ggrid(1, N_NODES / 64);             // 256 blocks
  dim3 sgrid(N_NODES / 32, NTILE);         // (512, 5)

  // L1: msg1 = relu(X @ Wc + bc) [tiled]; agg; h1 = relu(agg @ Wo1 + bo1)
  gemm_v2<true, true, false><<<ggrid, 512, 0, stream>>>(
      X, Wt + 0 * WSZ, biasP + 0 * DP, Y, nullptr, nullptr, nullptr, nullptr);
  spmm_tiled<<<sgrid, 256, 0, stream>>>(Y, row_ptr, csr_src, X);
  gemm_v2<true, false, false><<<ggrid, 512, 0, stream>>>(
      X, Wt + 3 * WSZ, biasP + 3 * DP, Y, nullptr, nullptr, nullptr, nullptr);
  // L2
  gemm_v2<true, true, false><<<ggrid, 512, 0, stream>>>(
      Y, Wt + 4 * WSZ, biasP + 4 * DP, X, nullptr, nullptr, nullptr, nullptr);
  spmm_tiled<<<sgrid, 256, 0, stream>>>(X, row_ptr, csr_src, Y);
  gemm_v2<true, false, false><<<ggrid, 512, 0, stream>>>(
      Y, Wt + 5 * WSZ, biasP + 5 * DP, X, nullptr, nullptr, nullptr, nullptr);
  // L3
  gemm_v2<true, true, false><<<ggrid, 512, 0, stream>>>(
      X, Wt + 6 * WSZ, biasP + 6 * DP, Y, nullptr, nullptr, nullptr, nullptr);
  spmm_tiled<<<sgrid, 256, 0, stream>>>(Y, row_ptr, csr_src, X);
  // final Wo3 GEMM with fused readout
  gemm_v2<true, false, true><<<ggrid, 512, 0, stream>>>(
      X, Wt + 7 * WSZ, biasP + 7 * DP, nullptr, W_ro, b_ro, gid, out);
}

// Round 7
// 208.324 us; speedup vs baseline: 1.2112x; 1.2112x over previous
//
#include <hip/hip_runtime.h>
#include <hip/hip_bf16.h>

#define N_NODES 16384
#define N_EDGES 262144
#define GD 300        // real feature dim
#define DP 320        // padded feature dim (pads are exact zeros)
#define N_GRAPHS 64
#define NTILE 5       // 5 column tiles of 64

typedef short bf16x8 __attribute__((ext_vector_type(8)));
typedef float f32x4 __attribute__((ext_vector_type(4)));

__device__ static inline unsigned short f2bf(float v) {
  __hip_bfloat16 b = __float2bfloat16(v);
  return __builtin_bit_cast(unsigned short, b);
}
__device__ static inline float bf2f(unsigned short u) {
  return __bfloat162float(__builtin_bit_cast(__hip_bfloat16, u));
}

#define GLOAD_LDS16(g, l)                                                    \
  __builtin_amdgcn_global_load_lds(                                          \
      (const __attribute__((address_space(1))) void*)(g),                    \
      (__attribute__((address_space(3))) void*)(l), 16, 0, 0)

// ================= bf16 MFMA GEMM v3 — counted-vmcnt 2-phase =================
// C[M,DP] = act(A[M,DP](bf16) @ W + bias), Wt[n][k] pre-transposed bf16.
// BM=64, BN=160, BK=64; 256 thr = 4 waves (2x2); per-wave 2x5 frags 16x16x32.
// LDS rows 128 B; 16B-slot s stores global slot s^(row&7) -> conflict-free
// ds_read_b128; staged via global_load_lds with pre-swizzled global source.
// K-loop: raw s_barrier + s_waitcnt vmcnt(7) — next tile's 7 loads stay in
// flight across the barrier (T3/T4); no __syncthreads() drain in the loop.
constexpr int BM = 64, BN = 160, BK = 64, NKT = DP / BK;  // 5 K-tiles
constexpr int A_BYTES = BM * 128;            // 8192
constexpr int B_BYTES = BN * 128;            // 20480
constexpr int BUF_BYTES = A_BYTES + B_BYTES; // 28672
constexpr size_t WSZ = (size_t)DP * DP;

template <bool RELU, bool TILED>
__global__ __launch_bounds__(256, 2) void gemm_v3(
    const unsigned short* __restrict__ A, const unsigned short* __restrict__ Wt,
    const float* __restrict__ biasP, unsigned short* __restrict__ C) {
  __shared__ __align__(16) char smem[2 * BUF_BYTES];  // 57344 B -> 2 blocks/CU

  const int bm = blockIdx.y * BM;
  const int bn = blockIdx.x * BN;
  const int t = threadIdx.x;
  const int w = t >> 6;   // wave 0..3
  const int l = t & 63;
  const int wr = w & 1;   // wave row -> rows wr*32..+31
  const int wc = w >> 1;  // wave col -> cols wc*80..+79

  const int lr = l >> 3;              // row within 8-row group
  const int sg = (l & 7) ^ lr;        // pre-swizzled global 16B-slot

  f32x4 acc[2][5] = {};

  auto stage = [&](int tk, int buf) {
    const int k0 = tk * BK;
    char* lb = smem + buf * BUF_BYTES;
#pragma unroll
    for (int i = 0; i < 7; ++i) {
      int g = w + 4 * i;  // 28 groups: 8 for A, 20 for Bt
      if (g < 8) {
        const unsigned short* gp =
            A + (size_t)(bm + g * 8 + lr) * DP + k0 + 8 * sg;
        GLOAD_LDS16(gp, lb + g * 1024);
      } else {
        int gb = g - 8;
        const unsigned short* gp =
            Wt + (size_t)(bn + gb * 8 + lr) * DP + k0 + 8 * sg;
        GLOAD_LDS16(gp, lb + A_BYTES + gb * 1024);
      }
    }
  };

  auto compute = [&](int buf) {
    const char* lA = smem + buf * BUF_BYTES;
    const char* lB = lA + A_BYTES;
#pragma unroll
    for (int ks = 0; ks < 2; ++ks) {
      bf16x8 a[2], b[5];
#pragma unroll
      for (int m = 0; m < 2; ++m) {
        int r = wr * 32 + m * 16 + (l & 15);
        int slot = (ks * 4 + (l >> 4)) ^ (r & 7);
        a[m] = *(const bf16x8*)(lA + r * 128 + slot * 16);
      }
#pragma unroll
      for (int n = 0; n < 5; ++n) {
        int r = wc * 80 + n * 16 + (l & 15);
        int slot = (ks * 4 + (l >> 4)) ^ (r & 7);
        b[n] = *(const bf16x8*)(lB + r * 128 + slot * 16);
      }
#pragma unroll
      for (int m = 0; m < 2; ++m)
#pragma unroll
        for (int n = 0; n < 5; ++n)
          acc[m][n] =
              __builtin_amdgcn_mfma_f32_16x16x32_bf16(a[m], b[n], acc[m][n], 0, 0, 0);
    }
  };

  stage(0, 0);
  for (int tk = 0; tk < NKT; ++tk) {
    // barrier 1: everyone finished reading buf[(tk+1)&1] (compute tk-1)
    __builtin_amdgcn_s_barrier();
    if (tk + 1 < NKT) {
      stage(tk + 1, (tk + 1) & 1);
      // wait only for tile tk's 7 loads (oldest); tile tk+1's 7 stay in flight
      asm volatile("s_waitcnt vmcnt(7)" ::: "memory");
    } else {
      asm volatile("s_waitcnt vmcnt(0)" ::: "memory");
    }
    // barrier 2: tile tk landed for ALL threads
    __builtin_amdgcn_s_barrier();
    compute(tk & 1);
  }

#pragma unroll
  for (int m = 0; m < 2; ++m) {
#pragma unroll
    for (int n = 0; n < 5; ++n) {
      int col = bn + wc * 80 + n * 16 + (l & 15);
      float bv = biasP[col];
#pragma unroll
      for (int r = 0; r < 4; ++r) {
        int row = bm + wr * 32 + m * 16 + (l >> 4) * 4 + r;
        float v = acc[m][n][r] + bv;
        if (RELU) v = fmaxf(v, 0.f);
        size_t idx;
        if (TILED)  // column-tile-major Mt[tile][row][64] for SpMM
          idx = ((size_t)(col >> 6) * N_NODES + row) * 64 + (col & 63);
        else
          idx = (size_t)row * DP + col;
        C[idx] = f2bf(v);
      }
    }
  }
}

// ================= CSR build =================
__global__ void hist_kernel(const int* __restrict__ dst, int* __restrict__ cnt) {
  int e = blockIdx.x * blockDim.x + threadIdx.x;
  if (e < N_EDGES) atomicAdd(&cnt[dst[e]], 1);
}

__global__ __launch_bounds__(256) void scan_kernel(
    const int* __restrict__ cnt, int* __restrict__ row_ptr, int* __restrict__ row_fill,
    float* __restrict__ out, int out_n) {
  if (threadIdx.x < out_n) out[threadIdx.x] = 0.f;  // zero d_out (fused)
  __shared__ int sums[256];
  const int t = threadIdx.x;
  const int base = t * 64;
  int s = 0;
  for (int i = 0; i < 64; ++i) s += cnt[base + i];
  sums[t] = s;
  __syncthreads();
  for (int off = 1; off < 256; off <<= 1) {
    int x = (t >= off) ? sums[t - off] : 0;
    __syncthreads();
    sums[t] += x;
    __syncthreads();
  }
  int run = sums[t] - s;
  for (int i = 0; i < 64; ++i) {
    int c = cnt[base + i];
    row_ptr[base + i] = run;
    row_fill[base + i] = run;
    run += c;
  }
  if (t == 255) row_ptr[N_NODES] = run;
}

__global__ void scatter_kernel(const int* __restrict__ src, const int* __restrict__ dst,
                               int* __restrict__ row_fill, int* __restrict__ csr_src) {
  int e = blockIdx.x * blockDim.x + threadIdx.x;
  if (e >= N_EDGES) return;
  int pos = atomicAdd(&row_fill[dst[e]], 1);
  csr_src[pos] = src[e];
}

// ========== SpMM aggregate: tiled gather, L2-resident per column phase ======
__global__ __launch_bounds__(256) void spmm_tiled(
    const unsigned short* __restrict__ Mt, const int* __restrict__ row_ptr,
    const int* __restrict__ csr_src, unsigned short* __restrict__ agg) {
  const int tile = blockIdx.y;
  const int wv = threadIdx.x >> 6;
  const int l = threadIdx.x & 63;
  const int g = l >> 3;    // node group
  const int cs = l & 7;    // 16B slot within 128B slice
  const int node = blockIdx.x * 32 + wv * 8 + g;
  const unsigned short* base = Mt + (size_t)tile * N_NODES * 64 + cs * 8;

  int j = row_ptr[node];
  const int j1 = row_ptr[node + 1];
  float acc[8] = {};
  for (; j + 4 <= j1; j += 4) {
    int s0 = csr_src[j], s1 = csr_src[j + 1];
    int s2 = csr_src[j + 2], s3 = csr_src[j + 3];
    bf16x8 v0 = *(const bf16x8*)(base + (size_t)s0 * 64);
    bf16x8 v1 = *(const bf16x8*)(base + (size_t)s1 * 64);
    bf16x8 v2 = *(const bf16x8*)(base + (size_t)s2 * 64);
    bf16x8 v3 = *(const bf16x8*)(base + (size_t)s3 * 64);
#pragma unroll
    for (int i = 0; i < 8; ++i)
      acc[i] += (bf2f(v0[i]) + bf2f(v1[i])) + (bf2f(v2[i]) + bf2f(v3[i]));
  }
  for (; j < j1; ++j) {
    bf16x8 v = *(const bf16x8*)(base + (size_t)csr_src[j] * 64);
#pragma unroll
    for (int i = 0; i < 8; ++i) acc[i] += bf2f(v[i]);
  }
  bf16x8 o;
#pragma unroll
  for (int i = 0; i < 8; ++i) o[i] = f2bf(acc[i]);
  *(bf16x8*)(agg + (size_t)node * DP + tile * 64 + cs * 8) = o;
}

// ================= readout: softmax + per-graph sum (LDS-binned) ============
__global__ __launch_bounds__(256) void readout_kernel(
    const unsigned short* __restrict__ h, const float* __restrict__ Wro,
    const float* __restrict__ bro, const int* __restrict__ gid,
    float* __restrict__ out) {
  __shared__ float wro[2 * DP];
  __shared__ float bins[2 * N_GRAPHS];
  const int t = threadIdx.x;
  if (t < 2 * N_GRAPHS) bins[t] = 0.f;
  for (int i = t; i < 2 * DP; i += 256) wro[i] = (i < 2 * GD) ? Wro[i] : 0.f;
  __syncthreads();

  const int w = t >> 6, l = t & 63;
  const float b0 = bro[0], b1 = bro[1];
  const int nodeBase = blockIdx.x * 64 + w * 16;
  for (int it = 0; it < 16; ++it) {
    int node = nodeBase + it;
    float d0 = 0.f, d1 = 0.f;
    if (l < 40) {
      bf16x8 v = *(const bf16x8*)(h + (size_t)node * DP + l * 8);
#pragma unroll
      for (int j = 0; j < 8; ++j) {
        float f = bf2f((unsigned short)v[j]);
        int k = l * 8 + j;
        d0 += f * wro[2 * k];
        d1 += f * wro[2 * k + 1];
      }
    }
#pragma unroll
    for (int off = 32; off; off >>= 1) {
      d0 += __shfl_down(d0, off);
      d1 += __shfl_down(d1, off);
    }
    if (l == 0) {
      d0 += b0; d1 += b1;
      float m = fmaxf(d0, d1);
      float e0 = expf(d0 - m), e1 = expf(d1 - m);
      float inv = 1.f / (e0 + e1);
      int g = gid[node];
      atomicAdd(&bins[2 * g], e0 * inv);
      atomicAdd(&bins[2 * g + 1], e1 * inv);
    }
  }
  __syncthreads();
  if (t < 2 * N_GRAPHS) {
    float v = bins[t];
    if (v != 0.f) atomicAdd(&out[t], v);
  }
}

// ================= conversions =================
__global__ void conv_feats(const float* __restrict__ nf, unsigned short* __restrict__ X) {
  int idx = blockIdx.x * 256 + threadIdx.x;  // over N_NODES * 40 groups of 8
  int r = idx / 40, j = idx - r * 40;
  int c0 = j * 8;
  const float* rp = nf + (size_t)r * GD + c0;
  bf16x8 o;
  if (c0 + 8 <= GD) {
    float4 a = *(const float4*)rp;
    float4 b = *(const float4*)(rp + 4);
    o[0] = f2bf(a.x); o[1] = f2bf(a.y); o[2] = f2bf(a.z); o[3] = f2bf(a.w);
    o[4] = f2bf(b.x); o[5] = f2bf(b.y); o[6] = f2bf(b.z); o[7] = f2bf(b.w);
  } else {
#pragma unroll
    for (int i = 0; i < 8; ++i) {
      int c = c0 + i;
      o[i] = f2bf(c < GD ? rp[i] : 0.f);
    }
  }
  *(bf16x8*)(X + (size_t)idx * 8) = o;
}

struct WPtrs {
  const float* W[7];   // [0..5] -> transposed (Wf1,Wo1,Wf2,Wo2,Wf3,Wo3), [6]=Wlift copy
  const float* b[5];   // biases for slots 3..7 (bo1,bf2,bo2,bf3,bo3)
};

// Wt slots: 0=Wc_t(computed), 1=Wf1t, 2=Wlift copy, 3=Wo1t, 4=Wf2t, 5=Wo2t,
// 6=Wf3t, 7=Wo3t. biasP slots: 0=bc, 1=zeros, 3..7 per Wt.
// LDS-tile transpose: coalesced fp32 reads AND coalesced bf16 writes.
__global__ __launch_bounds__(256) void conv_w(WPtrs p, unsigned short* __restrict__ Wt,
                                              float* __restrict__ biasP) {
  __shared__ unsigned short ld[64][33];
  const int wi = blockIdx.y;                  // 0..6
  const int kt = blockIdx.x / 5;              // 10 k-tiles of 32
  const int nt = blockIdx.x - kt * 5;         // 5 n-tiles of 64
  const int k0 = kt * 32, n0 = nt * 64;
  const int t = threadIdx.x;
  const float* W = p.W[wi];

  if (wi == 6) {  // plain copy (keep orientation), coalesced
#pragma unroll
    for (int ps = 0; ps < 8; ++ps) {
      int idx = t + 256 * ps;
      int rr = idx >> 6, cc = idx & 63;
      float v = (k0 + rr < GD && n0 + cc < GD) ? W[(size_t)(k0 + rr) * GD + n0 + cc] : 0.f;
      Wt[2 * WSZ + (size_t)(k0 + rr) * DP + n0 + cc] = f2bf(v);
    }
    return;
  }
  const int slot = (wi == 0) ? 1 : wi + 2;
#pragma unroll
  for (int ps = 0; ps < 8; ++ps) {
    int idx = t + 256 * ps;
    int rr = idx >> 6, cc = idx & 63;       // rr: k in tile, cc: n in tile
    float v = (k0 + rr < GD && n0 + cc < GD) ? W[(size_t)(k0 + rr) * GD + n0 + cc] : 0.f;
    ld[cc][rr] = f2bf(v);
  }
  __syncthreads();
#pragma unroll
  for (int ps = 0; ps < 8; ++ps) {
    int idx = t + 256 * ps;
    int nn = idx >> 5, kk = idx & 31;
    Wt[(size_t)slot * WSZ + (size_t)(n0 + nn) * DP + k0 + kk] = ld[nn][kk];
  }
  // fused bias copies for slots 3..7
  if (blockIdx.x == 0 && wi >= 1) {
    for (int i = t; i < DP; i += 256)
      biasP[(size_t)(wi + 2) * DP + i] = (i < GD) ? p.b[wi - 1][i] : 0.f;
  }
}

// bc[n] = bl @ Wf1[:,n] + bf1[n], wave-parallel using transposed bf16 Wf1t rows
__global__ __launch_bounds__(512) void bias_fuse(
    const unsigned short* __restrict__ Wf1t, const float* __restrict__ bl,
    const float* __restrict__ bf1, float* __restrict__ biasP) {
  const int w = threadIdx.x >> 6, l = threadIdx.x & 63;
  const int n = blockIdx.x * 8 + w;  // 0..319
  float s = 0.f;
  for (int j = l; j < GD; j += 64) s += bf2f(Wf1t[(size_t)n * DP + j]) * bl[j];
#pragma unroll
  for (int off = 32; off; off >>= 1) s += __shfl_down(s, off);
  if (l == 0) {
    biasP[n] = s + ((n < GD) ? bf1[n] : 0.f);  // slot 0 = bc
    biasP[DP + n] = 0.f;                        // slot 1 = zeros
  }
}

// ================= host =================
extern "C" void kernel_launch(void* const* d_in, const int* in_sizes, int n_in,
                              void* d_out, int out_size, void* d_ws, size_t ws_size,
                              hipStream_t stream) {
  const float* node_feats = (const float*)d_in[0];
  const float* W_lift = (const float*)d_in[1];
  const float* b_lift = (const float*)d_in[2];
  const float* Wf1 = (const float*)d_in[3];
  const float* bf1 = (const float*)d_in[4];
  const float* W_ro = (const float*)d_in[15];
  const float* b_ro = (const float*)d_in[16];
  const int* src = (const int*)d_in[17];
  const int* dst = (const int*)d_in[18];
  const int* gid = (const int*)d_in[19];
  float* out = (float*)d_out;

  WPtrs wp;
  wp.W[0] = Wf1;
  wp.W[1] = (const float*)d_in[5];   wp.b[0] = (const float*)d_in[6];   // Wo1 -> 3
  wp.W[2] = (const float*)d_in[7];   wp.b[1] = (const float*)d_in[8];   // Wf2 -> 4
  wp.W[3] = (const float*)d_in[9];   wp.b[2] = (const float*)d_in[10];  // Wo2 -> 5
  wp.W[4] = (const float*)d_in[11];  wp.b[3] = (const float*)d_in[12];  // Wf3 -> 6
  wp.W[5] = (const float*)d_in[13];  wp.b[4] = (const float*)d_in[14];  // Wo3 -> 7
  wp.W[6] = W_lift;                  // -> slot 2 (copy)

  char* p = (char*)d_ws;
  unsigned short* X = (unsigned short*)p;  p += (size_t)N_NODES * DP * 2;
  unsigned short* Y = (unsigned short*)p;  p += (size_t)N_NODES * DP * 2;
  unsigned short* Wt = (unsigned short*)p; p += (size_t)8 * WSZ * 2;
  float* biasP = (float*)p;                p += 8 * DP * 4;
  int* cnt = (int*)p;                      p += N_NODES * 4;
  int* row_ptr = (int*)p;                  p += (N_NODES + 16) * 4;
  int* row_fill = (int*)p;                 p += N_NODES * 4;
  int* csr_src = (int*)p;                  p += N_EDGES * 4;

  // --- CSR build (out-zeroing fused into scan) ---
  hipMemsetAsync(cnt, 0, N_NODES * sizeof(int), stream);
  hist_kernel<<<N_EDGES / 256, 256, 0, stream>>>(dst, cnt);
  scan_kernel<<<1, 256, 0, stream>>>(cnt, row_ptr, row_fill, out, out_size);
  scatter_kernel<<<N_EDGES / 256, 256, 0, stream>>>(src, dst, row_fill, csr_src);

  // --- conversions + lift-fold precompute ---
  conv_feats<<<(N_NODES * 40) / 256, 256, 0, stream>>>(node_feats, X);
  conv_w<<<dim3(50, 7), 256, 0, stream>>>(wp, Wt, biasP);
  bias_fuse<<<40, 512, 0, stream>>>(Wt + 1 * WSZ, b_lift, bf1, biasP);
  // Wc_t = Wf1t @ Wlift  (M=320)
  gemm_v3<false, false><<<dim3(2, 5), 256, 0, stream>>>(
      Wt + 1 * WSZ, Wt + 2 * WSZ, biasP + 1 * DP, Wt + 0 * WSZ);

  dim3 ggrid(2, N_NODES / 64);             // (2, 256) = 512 blocks
  dim3 sgrid(N_NODES / 32, NTILE);         // (512, 5)

  // L1: msg1 = relu(X @ Wc + bc) [tiled]; agg; h1 = relu(agg @ Wo1 + bo1)
  gemm_v3<true, true><<<ggrid, 256, 0, stream>>>(X, Wt + 0 * WSZ, biasP + 0 * DP, Y);
  spmm_tiled<<<sgrid, 256, 0, stream>>>(Y, row_ptr, csr_src, X);
  gemm_v3<true, false><<<ggrid, 256, 0, stream>>>(X, Wt + 3 * WSZ, biasP + 3 * DP, Y);
  // L2
  gemm_v3<true, true><<<ggrid, 256, 0, stream>>>(Y, Wt + 4 * WSZ, biasP + 4 * DP, X);
  spmm_tiled<<<sgrid, 256, 0, stream>>>(X, row_ptr, csr_src, Y);
  gemm_v3<true, false><<<ggrid, 256, 0, stream>>>(Y, Wt + 5 * WSZ, biasP + 5 * DP, X);
  // L3
  gemm_v3<true, true><<<ggrid, 256, 0, stream>>>(X, Wt + 6 * WSZ, biasP + 6 * DP, Y);
  spmm_tiled<<<sgrid, 256, 0, stream>>>(Y, row_ptr, csr_src, X);
  gemm_v3<true, false><<<ggrid, 256, 0, stream>>>(X, Wt + 7 * WSZ, biasP + 7 * DP, Y);

  // --- readout (h3 = Y) ---
  readout_kernel<<<N_NODES / 64, 256, 0, stream>>>(Y, W_ro, b_ro, gid, out);
}